// Round 7
// baseline (10480.318 us; speedup 1.0000x reference)
//
#include <hip/hip_runtime.h>
#include <hip/hip_cooperative_groups.h>

namespace cg = cooperative_groups;

#define VV 32000
#define EE 512
#define HH 1024
#define NB 64
#define NSTEP 32
#define SMEMN 8448  // floats: 4*64*33 = 33,792 B

typedef __attribute__((ext_vector_type(8))) short short8;
typedef __attribute__((ext_vector_type(4))) float f32x4;
typedef unsigned long long u64;

#define MFMA16(a, b, c) __builtin_amdgcn_mfma_f32_16x16x32_bf16((a), (b), (c), 0, 0, 0)

__device__ __forceinline__ unsigned short f2bf(float f) {
  unsigned int u = __float_as_uint(f);
  u += 0x7fffu + ((u >> 16) & 1u);
  return (unsigned short)(u >> 16);
}
__device__ __forceinline__ float bf2f(unsigned short b) {
  return __uint_as_float(((unsigned int)b) << 16);
}
__device__ __forceinline__ float sigmoidf_(float x) { return 1.0f / (1.0f + expf(-x)); }
__device__ __forceinline__ unsigned int ordkey(float f) {
  unsigned int u = __float_as_uint(f);
  return u ^ ((u >> 31) ? 0xFFFFFFFFu : 0x80000000u);
}
__device__ __forceinline__ float ordkey_inv(unsigned int u) {
  return __uint_as_float((u & 0x80000000u) ? (u ^ 0x80000000u) : ~u);
}

// ---------- prep: [Wih | Whh] -> bf16 main+res fragments grouped by (ublock, gate) ----------
__global__ __launch_bounds__(256) void prep_wcat(const float* __restrict__ Wih,
                                                 const float* __restrict__ Whh,
                                                 unsigned short* __restrict__ wm,
                                                 unsigned short* __restrict__ wr) {
  int ub = blockIdx.x / 3, g = blockIdx.x % 3;
  for (int e = threadIdx.x; e < 48 * 512; e += 256) {
    int ks = e >> 9, lane = (e >> 3) & 63, j = e & 7;
    int row = g * HH + ub * 16 + (lane & 15);
    int k = ks * 32 + ((lane >> 4) << 3) + j;
    float f = (k < EE) ? Wih[(size_t)row * EE + k] : Whh[(size_t)row * HH + (k - EE)];
    unsigned short m_ = f2bf(f);
    size_t idx = (((size_t)(ub * 3 + g) * 48 + ks) * 64 + lane) * 8 + j;
    wm[idx] = m_;
    wr[idx] = f2bf(f - bf2f(m_));
  }
}

// ---------- prep: fcW -> bf16 single fragments ----------
__global__ __launch_bounds__(256) void prep_wfc(const float* __restrict__ fcW,
                                                unsigned short* __restrict__ wfc) {
  int vg = blockIdx.x;
  for (int e = threadIdx.x; e < 32768; e += 256) {
    int ks = e >> 10, n = (e >> 9) & 1, lane = (e >> 3) & 63, j = e & 7;
    int v = vg * 32 + n * 16 + (lane & 15);
    int k = ks * 32 + ((lane >> 4) << 3) + j;
    wfc[(((size_t)vg * 32 + ks) * 2 + n) * 512 + lane * 8 + j] = f2bf(fcW[(size_t)v * HH + k]);
  }
}

// ---------- init: h0 (row-major + frags x8), x0 = emb[SOS] x8 ----------
__global__ __launch_bounds__(256) void init_kernel(
    const float* __restrict__ enc, const float* __restrict__ emb, float* __restrict__ h4a,
    unsigned short* __restrict__ ham, unsigned short* __restrict__ har,
    unsigned short* __restrict__ xam, unsigned short* __restrict__ xar) {
  int i = blockIdx.x * 256 + threadIdx.x;  // 65536
  int b = i >> 10, u = i & 1023;
  float hv = enc[i];
  h4a[i] = hv;
  unsigned short m_ = f2bf(hv);
  unsigned short r_ = f2bf(hv - bf2f(m_));
  size_t idx = (((size_t)(b >> 4) * 32 + (u >> 5)) * 64 + ((b & 15) + (((u >> 3) & 3) << 4))) * 8 + (u & 7);
#pragma unroll
  for (int c = 0; c < 8; ++c) {
    ham[(size_t)c * 65536 + idx] = m_;
    har[(size_t)c * 65536 + idx] = r_;
  }
  if (i < NB * EE) {
    int b2 = i >> 9, k = i & 511;
    float xv = emb[EE + k];  // token SOS=1
    unsigned short xm = f2bf(xv);
    unsigned short xr = f2bf(xv - bf2f(xm));
    size_t xi = (((size_t)(b2 >> 4) * 16 + (k >> 5)) * 64 + ((b2 & 15) + (((k >> 3) & 3) << 4))) * 8 + (k & 7);
#pragma unroll
    for (int c = 0; c < 8; ++c) {
      xam[(size_t)c * 32768 + xi] = xm;
      xar[(size_t)c * 32768 + xi] = xr;
    }
  }
}

// ================= device phase bodies (shared by coop kernel and fallback) =================

__device__ __forceinline__ void gru_phase(
    int bid, int tid, float* smemf,
    const unsigned short* xam, const unsigned short* xar,
    const unsigned short* him, const unsigned short* hir,
    const float* hin, float* hout,
    const unsigned short* wcm, const unsigned short* wcr,
    const float* bih, const float* bhh,
    unsigned short* hom, unsigned short* hor) {
  if (bid >= 256) return;
  float(*gred)[16][65] = (float(*)[16][65])smemf;
  const int lane = tid & 63, w = tid >> 6, cp = bid & 7;
  const int ub = bid >> 2, mg = bid & 3;
  f32x4 aR{}, aZ{}, aNX{}, aNH{};
  const short8* XM = (const short8*)(xam + (size_t)cp * 32768);
  const short8* XR = (const short8*)(xar + (size_t)cp * 32768);
  const short8* HM = (const short8*)(him + (size_t)cp * 65536);
  const short8* HR = (const short8*)(hir + (size_t)cp * 65536);
  const short8* WM = (const short8*)wcm;
  const short8* WR = (const short8*)wcr;
#pragma unroll
  for (int s = 0; s < 12; ++s) {
    int ks = w * 12 + s;
    short8 am, ar;
    if (ks < 16) {
      int o = (mg * 16 + ks) * 64 + lane;
      am = XM[o]; ar = XR[o];
    } else {
      int o = (mg * 32 + (ks - 16)) * 64 + lane;
      am = HM[o]; ar = HR[o];
    }
    {
      int o = ((ub * 3 + 0) * 48 + ks) * 64 + lane;
      short8 wmv = WM[o], wrv = WR[o];
      aR = MFMA16(am, wmv, aR); aR = MFMA16(ar, wmv, aR); aR = MFMA16(am, wrv, aR);
    }
    {
      int o = ((ub * 3 + 1) * 48 + ks) * 64 + lane;
      short8 wmv = WM[o], wrv = WR[o];
      aZ = MFMA16(am, wmv, aZ); aZ = MFMA16(ar, wmv, aZ); aZ = MFMA16(am, wrv, aZ);
    }
    {
      int o = ((ub * 3 + 2) * 48 + ks) * 64 + lane;
      short8 wmv = WM[o], wrv = WR[o];
      if (ks < 16) {
        aNX = MFMA16(am, wmv, aNX); aNX = MFMA16(ar, wmv, aNX); aNX = MFMA16(am, wrv, aNX);
      } else {
        aNH = MFMA16(am, wmv, aNH); aNH = MFMA16(ar, wmv, aNH); aNH = MFMA16(am, wrv, aNH);
      }
    }
  }
#pragma unroll
  for (int reg = 0; reg < 4; ++reg) {
    int rr = ((lane >> 4) << 2) + reg, c = lane & 15;
    gred[w][rr][c] = aR[reg];
    gred[w][rr][16 + c] = aZ[reg];
    gred[w][rr][32 + c] = aNX[reg];
    gred[w][rr][48 + c] = aNH[reg];
  }
  __syncthreads();
  const int mrow = tid >> 4, uu = tid & 15;
  float R = 0.f, Z = 0.f, NX = 0.f, NH = 0.f;
#pragma unroll
  for (int q = 0; q < 4; ++q) {
    R += gred[q][mrow][uu];
    Z += gred[q][mrow][16 + uu];
    NX += gred[q][mrow][32 + uu];
    NH += gred[q][mrow][48 + uu];
  }
  const int b = mg * 16 + mrow, u = ub * 16 + uu;
  float r = sigmoidf_(R + bih[u] + bhh[u]);
  float z = sigmoidf_(Z + bih[HH + u] + bhh[HH + u]);
  float n = tanhf(NX + bih[2 * HH + u] + r * (NH + bhh[2 * HH + u]));
  float hold = hin[b * HH + u];
  float hn = (1.0f - z) * n + z * hold;
  hout[b * HH + u] = hn;
  unsigned short m_ = f2bf(hn);
  unsigned short r_ = f2bf(hn - bf2f(m_));
  size_t idx = (((size_t)(b >> 4) * 32 + (u >> 5)) * 64 + ((b & 15) + (((u >> 3) & 3) << 4))) * 8 + (u & 7);
#pragma unroll
  for (int c = 0; c < 8; ++c) {
    hom[(size_t)c * 65536 + idx] = m_;
    hor[(size_t)c * 65536 + idx] = r_;
  }
  __syncthreads();
}

__device__ __forceinline__ void fc_phase(
    int bid, int tid, float* smemf,
    const unsigned short* hom, const unsigned short* hor,
    const unsigned short* wfc, const float* fcb,
    float* out, u64* blkkeys, int t) {
  if (bid >= 250) return;
  float(*red)[64][33] = (float(*)[64][33])smemf;
  const int lane = tid & 63, w = tid >> 6, cp = bid & 7;
  const short8* HM = (const short8*)(hom + (size_t)cp * 65536);
  const short8* HR = (const short8*)(hor + (size_t)cp * 65536);
  const short8* W = (const short8*)wfc;
#pragma unroll 1
  for (int vp = 0; vp < 2; ++vp) {
    const int vg0 = bid * 4 + vp * 2;
    f32x4 acc[4][4] = {};  // [m][v2*2+nt]
#pragma unroll
    for (int s = 0; s < 8; ++s) {
      int ks = w * 8 + s;
      short8 am[4], ar[4];
#pragma unroll
      for (int m = 0; m < 4; ++m) {
        int o = (m * 32 + ks) * 64 + lane;
        am[m] = HM[o]; ar[m] = HR[o];
      }
#pragma unroll
      for (int v2 = 0; v2 < 2; ++v2) {
        short8 wv0 = W[(((size_t)(vg0 + v2) * 32 + ks) * 2 + 0) * 64 + lane];
        short8 wv1 = W[(((size_t)(vg0 + v2) * 32 + ks) * 2 + 1) * 64 + lane];
#pragma unroll
        for (int m = 0; m < 4; ++m) {
          acc[m][v2 * 2 + 0] = MFMA16(am[m], wv0, acc[m][v2 * 2 + 0]);
          acc[m][v2 * 2 + 0] = MFMA16(ar[m], wv0, acc[m][v2 * 2 + 0]);
          acc[m][v2 * 2 + 1] = MFMA16(am[m], wv1, acc[m][v2 * 2 + 1]);
          acc[m][v2 * 2 + 1] = MFMA16(ar[m], wv1, acc[m][v2 * 2 + 1]);
        }
      }
    }
#pragma unroll 1
    for (int v2 = 0; v2 < 2; ++v2) {
      const int vg = vg0 + v2;
      __syncthreads();
#pragma unroll
      for (int m = 0; m < 4; ++m)
#pragma unroll
        for (int nt = 0; nt < 2; ++nt)
#pragma unroll
          for (int reg = 0; reg < 4; ++reg)
            red[w][m * 16 + ((lane >> 4) << 2) + reg][nt * 16 + (lane & 15)] = acc[m][v2 * 2 + nt][reg];
      __syncthreads();
      const int b = tid >> 2, c0 = (tid & 3) << 3;
      u64 k1 = 0;
      size_t ro = ((size_t)b * NSTEP + t) * VV + (size_t)vg * 32 + c0;
#pragma unroll
      for (int e = 0; e < 8; ++e) {
        int c = c0 + e;
        float v = red[0][b][c] + red[1][b][c] + red[2][b][c] + red[3][b][c] + fcb[vg * 32 + c];
        out[ro + e] = v;
        u64 key = ((u64)ordkey(v) << 32) | (u64)(0xFFFFFFFFu - (unsigned)(vg * 32 + c));
        if (key > k1) k1 = key;
      }
      {
        u64 o1 = __shfl_xor(k1, 1, 64);
        if (o1 > k1) k1 = o1;
        u64 o2 = __shfl_xor(k1, 2, 64);
        if (o2 > k1) k1 = o2;
      }
      if ((tid & 3) == 0) blkkeys[(size_t)b * 1000 + vg] = k1;
    }
  }
}

__device__ __forceinline__ void sel_phase(
    int bid, int tid, float* smemf,
    const float* out, const u64* blkkeys,
    const float* fcW, const float* fcb, const float* emb, const float* hout,
    unsigned short* xam, unsigned short* xar, int t) {
  if (bid >= 64) return;
  u64* skey = (u64*)smemf;                  // 2048 B
  int* sint = (int*)((char*)smemf + 2048);  // [0]=scnt [1]=stok
  int* scand = (int*)((char*)smemf + 2064); // 32 ints
  u64* rkey = (u64*)((char*)smemf + 2200);  // 32 u64 (2200 % 8 == 0)
  const int b = bid;

  const u64* kb = blkkeys + (size_t)b * 1000;
  u64 mk = 0;
  for (int i = tid; i < 1000; i += 256) {
    u64 k = kb[i];
    if (k > mk) mk = k;
  }
  skey[tid] = mk;
  __syncthreads();
  for (int off = 128; off > 0; off >>= 1) {
    if (tid < off && skey[tid + off] > skey[tid]) skey[tid] = skey[tid + off];
    __syncthreads();
  }
  const u64 topkey = skey[0];
  const unsigned va = 0xFFFFFFFFu - (unsigned)(topkey & 0xFFFFFFFFu);
  const float Mf = ordkey_inv((unsigned)(topkey >> 32));
  if (tid == 0) { sint[0] = 1; scand[0] = (int)va; }
  __syncthreads();
  const float thr = Mf - 0.10f;

  const float* rowp = out + ((size_t)b * NSTEP + t) * VV;
  for (int v = tid; v < VV; v += 256) {
    float x = rowp[v];
    if (x >= thr && v != (int)va) {
      int p = atomicAdd(&sint[0], 1);
      if (p < 32) scand[p] = v;
    }
  }
  __syncthreads();
  int nc = sint[0] < 32 ? sint[0] : 32;

  const int wv_ = tid >> 6, ln = tid & 63;
  for (int ci = wv_; ci < nc; ci += 4) {
    int v = scand[ci];
    float p = 0.f;
#pragma unroll
    for (int q = 0; q < 16; ++q)
      p += hout[b * HH + ln + (q << 6)] * fcW[(size_t)v * HH + ln + (q << 6)];
#pragma unroll
    for (int d = 1; d < 64; d <<= 1) p += __shfl_xor(p, d);
    if (ln == 0)
      rkey[ci] = ((u64)ordkey(p + fcb[v]) << 32) | (u64)(0xFFFFFFFFu - (unsigned)v);
  }
  __syncthreads();
  if (tid == 0) {
    u64 bk = 0;
    for (int ci = 0; ci < nc; ++ci)
      if (rkey[ci] > bk) bk = rkey[ci];
    sint[1] = (int)(0xFFFFFFFFu - (unsigned)(bk & 0xFFFFFFFFu));
  }
  __syncthreads();

  const int tok = sint[1];
  for (int k = tid; k < EE; k += 256) {
    float xv = emb[(size_t)tok * EE + k];
    unsigned short xm = f2bf(xv);
    unsigned short xr = f2bf(xv - bf2f(xm));
    size_t xi = (((size_t)(b >> 4) * 16 + (k >> 5)) * 64 + ((b & 15) + (((k >> 3) & 3) << 4))) * 8 + (k & 7);
#pragma unroll
    for (int c = 0; c < 8; ++c) {
      xam[(size_t)c * 32768 + xi] = xm;
      xar[(size_t)c * 32768 + xi] = xr;
    }
  }
}

// ================= cooperative fused decoder: grid 256 (capacity-safe) =================
__global__ __launch_bounds__(256) void decode_kernel(
    unsigned short* xam, unsigned short* xar,
    unsigned short* hAm, unsigned short* hAr,
    unsigned short* hBm, unsigned short* hBr,
    float* h4a, float* h4b,
    const unsigned short* wcm, const unsigned short* wcr,
    const float* bih, const float* bhh,
    const unsigned short* wfc, const float* fcb,
    float* out, u64* blkkeys,
    const float* fcW, const float* emb) {
  cg::grid_group grid = cg::this_grid();
  __shared__ __align__(16) float smemf[SMEMN];
  const int bid = blockIdx.x, tid = threadIdx.x;

#pragma unroll 1
  for (int t = 0; t < NSTEP; ++t) {
    const unsigned short* him = (t & 1) ? hBm : hAm;
    const unsigned short* hir = (t & 1) ? hBr : hAr;
    unsigned short* hom = (t & 1) ? hAm : hBm;
    unsigned short* hor = (t & 1) ? hAr : hBr;
    const float* hin = (t & 1) ? h4b : h4a;
    float* hout = (t & 1) ? h4a : h4b;

    gru_phase(bid, tid, smemf, xam, xar, him, hir, hin, hout, wcm, wcr, bih, bhh, hom, hor);
    __threadfence(); grid.sync(); __threadfence();

    fc_phase(bid, tid, smemf, hom, hor, wfc, fcb, out, blkkeys, t);
    __threadfence(); grid.sync(); __threadfence();

    sel_phase(bid, tid, smemf, out, blkkeys, fcW, fcb, emb, hout, xam, xar, t);
    __threadfence(); grid.sync(); __threadfence();
  }
}

// ================= fallback per-step kernels (same phase bodies) =================
__global__ __launch_bounds__(256) void gru_k(
    const unsigned short* xam, const unsigned short* xar,
    const unsigned short* him, const unsigned short* hir,
    const float* hin, float* hout,
    const unsigned short* wcm, const unsigned short* wcr,
    const float* bih, const float* bhh,
    unsigned short* hom, unsigned short* hor) {
  __shared__ __align__(16) float smemf[SMEMN];
  gru_phase(blockIdx.x, threadIdx.x, smemf, xam, xar, him, hir, hin, hout, wcm, wcr, bih, bhh, hom, hor);
}
__global__ __launch_bounds__(256) void fc_k(
    const unsigned short* hom, const unsigned short* hor,
    const unsigned short* wfc, const float* fcb,
    float* out, u64* blkkeys, int t) {
  __shared__ __align__(16) float smemf[SMEMN];
  fc_phase(blockIdx.x, threadIdx.x, smemf, hom, hor, wfc, fcb, out, blkkeys, t);
}
__global__ __launch_bounds__(256) void sel_k(
    const float* out, const u64* blkkeys,
    const float* fcW, const float* fcb, const float* emb, const float* hout,
    unsigned short* xam, unsigned short* xar, int t) {
  __shared__ __align__(16) float smemf[SMEMN];
  sel_phase(blockIdx.x, threadIdx.x, smemf, out, blkkeys, fcW, fcb, emb, hout, xam, xar, t);
}

// ---------- final: in-place log-softmax per (b,t) row ----------
__global__ __launch_bounds__(256) void lsm_kernel(float* __restrict__ out) {
  const int bt = blockIdx.x;
  const int tid = threadIdx.x;
  float* row = out + (size_t)bt * VV;
  float4* r4 = (float4*)row;
  __shared__ float mred[256], sred[256];
  float m = -INFINITY, s = 0.f;
  for (int i = tid; i < VV / 4; i += 256) {
    float4 v = r4[i];
#pragma unroll
    for (int c = 0; c < 4; ++c) {
      float x = (&v.x)[c];
      if (x > m) { s = s * expf(m - x) + 1.0f; m = x; }
      else s += expf(x - m);
    }
  }
  mred[tid] = m; sred[tid] = s;
  __syncthreads();
  for (int off = 128; off > 0; off >>= 1) {
    if (tid < off) {
      float m1 = mred[tid], s1 = sred[tid];
      float m2 = mred[tid + off], s2 = sred[tid + off];
      float M = fmaxf(m1, m2);
      mred[tid] = M;
      sred[tid] = s1 * expf(m1 - M) + s2 * expf(m2 - M);
    }
    __syncthreads();
  }
  const float lse = mred[0] + logf(sred[0]);
  for (int i = tid; i < VV / 4; i += 256) {
    float4 v = r4[i];
    v.x -= lse; v.y -= lse; v.z -= lse; v.w -= lse;
    r4[i] = v;
  }
}

// ---------- hT tail ----------
__global__ __launch_bounds__(256) void final_kernel(const float* __restrict__ h4,
                                                    float* __restrict__ out) {
  int i = blockIdx.x * 256 + threadIdx.x;  // 65536
  out[(size_t)NB * NSTEP * VV + i] = h4[i];
}

extern "C" void kernel_launch(void* const* d_in, const int* in_sizes, int n_in,
                              void* d_out, int out_size, void* d_ws, size_t ws_size,
                              hipStream_t stream) {
  const float* enc = (const float*)d_in[1];
  const float* emb = (const float*)d_in[2];
  const float* Wih = (const float*)d_in[3];
  const float* Whh = (const float*)d_in[4];
  const float* bih = (const float*)d_in[5];
  const float* bhh = (const float*)d_in[6];
  const float* fcW = (const float*)d_in[7];
  const float* fcb = (const float*)d_in[8];
  float* out = (float*)d_out;

  char* ws = (char*)d_ws;
  unsigned short* wfc = (unsigned short*)ws; ws += (size_t)32768000 * 2;   // 65.5 MB
  unsigned short* wcm = (unsigned short*)ws; ws += (size_t)4718592 * 2;    // 9.44 MB
  unsigned short* wcr = (unsigned short*)ws; ws += (size_t)4718592 * 2;    // 9.44 MB
  unsigned short* hAm = (unsigned short*)ws; ws += (size_t)8 * 65536 * 2;  // 1 MB (x8 replicas)
  unsigned short* hAr = (unsigned short*)ws; ws += (size_t)8 * 65536 * 2;
  unsigned short* hBm = (unsigned short*)ws; ws += (size_t)8 * 65536 * 2;
  unsigned short* hBr = (unsigned short*)ws; ws += (size_t)8 * 65536 * 2;
  unsigned short* xam = (unsigned short*)ws; ws += (size_t)8 * 32768 * 2;  // 512 KB
  unsigned short* xar = (unsigned short*)ws; ws += (size_t)8 * 32768 * 2;
  float* h4a = (float*)ws; ws += (size_t)NB * HH * 4;
  float* h4b = (float*)ws; ws += (size_t)NB * HH * 4;
  u64* blkkeys = (u64*)ws; ws += (size_t)NB * 1000 * 8;  // 512 KB

  prep_wfc<<<1000, 256, 0, stream>>>(fcW, wfc);
  prep_wcat<<<192, 256, 0, stream>>>(Wih, Whh, wcm, wcr);
  init_kernel<<<256, 256, 0, stream>>>(enc, emb, h4a, hAm, hAr, xam, xar);

  void* args[] = {&xam, &xar, &hAm, &hAr, &hBm, &hBr, &h4a, &h4b,
                  &wcm, &wcr, &bih, &bhh, &wfc, &fcb, &out, &blkkeys, &fcW, &emb};
  hipError_t cerr = hipLaunchCooperativeKernel((void*)decode_kernel, dim3(256), dim3(256),
                                               args, 0, stream);
  if (cerr != hipSuccess) {
    // fallback: per-step kernel sequence with identical phase bodies/numerics
    for (int t = 0; t < NSTEP; ++t) {
      const unsigned short* him = (t & 1) ? hBm : hAm;
      const unsigned short* hir = (t & 1) ? hBr : hAr;
      unsigned short* hom = (t & 1) ? hAm : hBm;
      unsigned short* hor = (t & 1) ? hAr : hBr;
      const float* hin = (t & 1) ? h4b : h4a;
      float* hout = (t & 1) ? h4a : h4b;
      gru_k<<<256, 256, 0, stream>>>(xam, xar, him, hir, hin, hout, wcm, wcr, bih, bhh, hom, hor);
      fc_k<<<250, 256, 0, stream>>>(hom, hor, wfc, fcb, out, blkkeys, t);
      sel_k<<<64, 256, 0, stream>>>(out, blkkeys, fcW, fcb, emb, hout, xam, xar, t);
    }
  }

  lsm_kernel<<<2048, 256, 0, stream>>>(out);
  final_kernel<<<256, 256, 0, stream>>>(h4a, out);  // t=31 wrote h4a
}

// Round 9
// 5550.164 us; speedup vs baseline: 1.8883x; 1.8883x over previous
//
#include <hip/hip_runtime.h>

#define VV 32000
#define EE 512
#define HH 1024
#define NB 64
#define NSTEP 32

typedef __attribute__((ext_vector_type(8))) short short8;
typedef __attribute__((ext_vector_type(4))) float f32x4;
typedef unsigned long long u64;

#define MFMA16(a, b, c) __builtin_amdgcn_mfma_f32_16x16x32_bf16((a), (b), (c), 0, 0, 0)

__device__ __forceinline__ unsigned short f2bf(float f) {
  unsigned int u = __float_as_uint(f);
  u += 0x7fffu + ((u >> 16) & 1u);
  return (unsigned short)(u >> 16);
}
__device__ __forceinline__ float bf2f(unsigned short b) {
  return __uint_as_float(((unsigned int)b) << 16);
}
__device__ __forceinline__ float sigmoidf_(float x) { return 1.0f / (1.0f + expf(-x)); }
__device__ __forceinline__ unsigned int ordkey(float f) {
  unsigned int u = __float_as_uint(f);
  return u ^ ((u >> 31) ? 0xFFFFFFFFu : 0x80000000u);
}
__device__ __forceinline__ float ordkey_inv(unsigned int u) {
  return __uint_as_float((u & 0x80000000u) ? (u ^ 0x80000000u) : ~u);
}

// ---------- prep: [Wih | Whh] -> bf16 main+res fragments ----------
__global__ __launch_bounds__(256) void prep_wcat(const float* __restrict__ Wih,
                                                 const float* __restrict__ Whh,
                                                 unsigned short* __restrict__ wm,
                                                 unsigned short* __restrict__ wr) {
  int ub = blockIdx.x / 3, g = blockIdx.x % 3;
  for (int e = threadIdx.x; e < 48 * 512; e += 256) {
    int ks = e >> 9, lane = (e >> 3) & 63, j = e & 7;
    int row = g * HH + ub * 16 + (lane & 15);
    int k = ks * 32 + ((lane >> 4) << 3) + j;
    float f = (k < EE) ? Wih[(size_t)row * EE + k] : Whh[(size_t)row * HH + (k - EE)];
    unsigned short m_ = f2bf(f);
    size_t idx = (((size_t)(ub * 3 + g) * 48 + ks) * 64 + lane) * 8 + j;
    wm[idx] = m_;
    wr[idx] = f2bf(f - bf2f(m_));
  }
}

// ---------- prep: fcW -> bf16 single fragments ----------
__global__ __launch_bounds__(256) void prep_wfc(const float* __restrict__ fcW,
                                                unsigned short* __restrict__ wfc) {
  int vg = blockIdx.x;
  for (int e = threadIdx.x; e < 32768; e += 256) {
    int ks = e >> 10, n = (e >> 9) & 1, lane = (e >> 3) & 63, j = e & 7;
    int v = vg * 32 + n * 16 + (lane & 15);
    int k = ks * 32 + ((lane >> 4) << 3) + j;
    wfc[(((size_t)vg * 32 + ks) * 2 + n) * 512 + lane * 8 + j] = f2bf(fcW[(size_t)v * HH + k]);
  }
}

// ---------- init: h0 (row-major + frags), x0 = emb[SOS] ----------
__global__ __launch_bounds__(256) void init_kernel(
    const float* __restrict__ enc, const float* __restrict__ emb, float* __restrict__ h4a,
    unsigned short* __restrict__ ham, unsigned short* __restrict__ har,
    unsigned short* __restrict__ xam, unsigned short* __restrict__ xar) {
  int i = blockIdx.x * 256 + threadIdx.x;  // 65536
  int b = i >> 10, u = i & 1023;
  float hv = enc[i];
  h4a[i] = hv;
  unsigned short m_ = f2bf(hv);
  size_t idx = (((size_t)(b >> 4) * 32 + (u >> 5)) * 64 + ((b & 15) + (((u >> 3) & 3) << 4))) * 8 + (u & 7);
  ham[idx] = m_;
  har[idx] = f2bf(hv - bf2f(m_));
  if (i < NB * EE) {
    int b2 = i >> 9, k = i & 511;
    float xv = emb[EE + k];  // token SOS=1
    unsigned short xm = f2bf(xv);
    size_t xi = (((size_t)(b2 >> 4) * 16 + (k >> 5)) * 64 + ((b2 & 15) + (((k >> 3) & 3) << 4))) * 8 + (k & 7);
    xam[xi] = xm;
    xar[xi] = f2bf(xv - bf2f(xm));
  }
}

// ================= phase bodies (exact r5 logic) =================

__device__ __forceinline__ void gru_body(
    int bid, int tid, float (*red)[16][65],
    const unsigned short* xam, const unsigned short* xar,
    const unsigned short* him, const unsigned short* hir,
    const float* h4in, float* h4out,
    const unsigned short* wm, const unsigned short* wrs,
    const float* bih, const float* bhh,
    unsigned short* hom, unsigned short* hor) {
  const int lane = tid & 63, w = tid >> 6;
  const int ub = bid >> 2, mg = bid & 3;
  f32x4 aR{}, aZ{}, aNX{}, aNH{};
  const short8* XM = (const short8*)xam;
  const short8* XR = (const short8*)xar;
  const short8* HM = (const short8*)him;
  const short8* HR = (const short8*)hir;
  const short8* WM = (const short8*)wm;
  const short8* WR = (const short8*)wrs;
#pragma unroll
  for (int s = 0; s < 12; ++s) {
    int ks = w * 12 + s;
    short8 am, ar;
    if (ks < 16) {
      int o = (mg * 16 + ks) * 64 + lane;
      am = XM[o]; ar = XR[o];
    } else {
      int o = (mg * 32 + (ks - 16)) * 64 + lane;
      am = HM[o]; ar = HR[o];
    }
    {
      int o = ((ub * 3 + 0) * 48 + ks) * 64 + lane;
      short8 wmv = WM[o], wrv = WR[o];
      aR = MFMA16(am, wmv, aR); aR = MFMA16(ar, wmv, aR); aR = MFMA16(am, wrv, aR);
    }
    {
      int o = ((ub * 3 + 1) * 48 + ks) * 64 + lane;
      short8 wmv = WM[o], wrv = WR[o];
      aZ = MFMA16(am, wmv, aZ); aZ = MFMA16(ar, wmv, aZ); aZ = MFMA16(am, wrv, aZ);
    }
    {
      int o = ((ub * 3 + 2) * 48 + ks) * 64 + lane;
      short8 wmv = WM[o], wrv = WR[o];
      if (ks < 16) {
        aNX = MFMA16(am, wmv, aNX); aNX = MFMA16(ar, wmv, aNX); aNX = MFMA16(am, wrv, aNX);
      } else {
        aNH = MFMA16(am, wmv, aNH); aNH = MFMA16(ar, wmv, aNH); aNH = MFMA16(am, wrv, aNH);
      }
    }
  }
#pragma unroll
  for (int reg = 0; reg < 4; ++reg) {
    int rr = ((lane >> 4) << 2) + reg, c = lane & 15;
    red[w][rr][c] = aR[reg];
    red[w][rr][16 + c] = aZ[reg];
    red[w][rr][32 + c] = aNX[reg];
    red[w][rr][48 + c] = aNH[reg];
  }
  __syncthreads();
  const int mrow = tid >> 4, uu = tid & 15;
  float R = 0.f, Z = 0.f, NX = 0.f, NH = 0.f;
#pragma unroll
  for (int q = 0; q < 4; ++q) {
    R += red[q][mrow][uu];
    Z += red[q][mrow][16 + uu];
    NX += red[q][mrow][32 + uu];
    NH += red[q][mrow][48 + uu];
  }
  const int b = mg * 16 + mrow, u = ub * 16 + uu;
  float r = sigmoidf_(R + bih[u] + bhh[u]);
  float z = sigmoidf_(Z + bih[HH + u] + bhh[HH + u]);
  float n = tanhf(NX + bih[2 * HH + u] + r * (NH + bhh[2 * HH + u]));
  float hold = h4in[b * HH + u];
  float hn = (1.0f - z) * n + z * hold;
  h4out[b * HH + u] = hn;
  unsigned short m_ = f2bf(hn);
  size_t idx = (((size_t)(b >> 4) * 32 + (u >> 5)) * 64 + ((b & 15) + (((u >> 3) & 3) << 4))) * 8 + (u & 7);
  hom[idx] = m_;
  hor[idx] = f2bf(hn - bf2f(m_));
}

__device__ __forceinline__ void fc_body(
    int bid, int tid, float (*red)[64][33],
    const unsigned short* ham, const unsigned short* har,
    const unsigned short* wfc, const float* fcb,
    float* out, u64* blkkeys, int t) {
  const int lane = tid & 63, w = tid >> 6;
  const int vg = bid;
  f32x4 acc[4][2] = {};
  const short8* HM = (const short8*)ham;
  const short8* HR = (const short8*)har;
  const short8* W = (const short8*)wfc;
#pragma unroll
  for (int s = 0; s < 8; ++s) {
    int ks = w * 8 + s;
    short8 am[4], ar[4], wv[2];
#pragma unroll
    for (int m = 0; m < 4; ++m) {
      int o = (m * 32 + ks) * 64 + lane;
      am[m] = HM[o]; ar[m] = HR[o];
    }
#pragma unroll
    for (int nt = 0; nt < 2; ++nt) wv[nt] = W[((vg * 32 + ks) * 2 + nt) * 64 + lane];
#pragma unroll
    for (int m = 0; m < 4; ++m)
#pragma unroll
      for (int nt = 0; nt < 2; ++nt) {
        acc[m][nt] = MFMA16(am[m], wv[nt], acc[m][nt]);
        acc[m][nt] = MFMA16(ar[m], wv[nt], acc[m][nt]);
      }
  }
#pragma unroll
  for (int m = 0; m < 4; ++m)
#pragma unroll
    for (int nt = 0; nt < 2; ++nt)
#pragma unroll
      for (int reg = 0; reg < 4; ++reg)
        red[w][m * 16 + ((lane >> 4) << 2) + reg][nt * 16 + (lane & 15)] = acc[m][nt][reg];
  __syncthreads();
  const int b = tid >> 2, c0 = (tid & 3) << 3;
  u64 k1 = 0;
  size_t ro = ((size_t)b * NSTEP + t) * VV + (size_t)vg * 32 + c0;
#pragma unroll
  for (int e = 0; e < 8; ++e) {
    int c = c0 + e;
    float v = red[0][b][c] + red[1][b][c] + red[2][b][c] + red[3][b][c] + fcb[vg * 32 + c];
    out[ro + e] = v;
    u64 key = ((u64)ordkey(v) << 32) | (u64)(0xFFFFFFFFu - (unsigned)(vg * 32 + c));
    if (key > k1) k1 = key;
  }
  {
    u64 o1 = __shfl_xor(k1, 1, 64);
    if (o1 > k1) k1 = o1;
    u64 o2 = __shfl_xor(k1, 2, 64);
    if (o2 > k1) k1 = o2;
  }
  if ((tid & 3) == 0) blkkeys[(size_t)b * 1000 + vg] = k1;
}

__device__ __forceinline__ void sel_body(
    int bid, int tid, u64* skey, int* sflags, int* scand, u64* rkey,
    const float* out, const u64* blkkeys,
    const float* fcW, const float* fcb,
    const float* emb, const float* h4,
    unsigned short* xam, unsigned short* xar, int t) {
  const int b = bid;
  // Phase 0: approx global max from the 1000 per-block keys
  const u64* kb = blkkeys + (size_t)b * 1000;
  u64 mk = 0;
  for (int i = tid; i < 1000; i += 256) {
    u64 k = kb[i];
    if (k > mk) mk = k;
  }
  skey[tid] = mk;
  __syncthreads();
  for (int off = 128; off > 0; off >>= 1) {
    if (tid < off && skey[tid + off] > skey[tid]) skey[tid] = skey[tid + off];
    __syncthreads();
  }
  const u64 topkey = skey[0];
  const unsigned va = 0xFFFFFFFFu - (unsigned)(topkey & 0xFFFFFFFFu);
  const float Mf = ordkey_inv((unsigned)(topkey >> 32));
  if (tid == 0) { sflags[0] = 1; scand[0] = (int)va; }
  __syncthreads();
  const float thr = Mf - 0.10f;

  // Phase 1: full-row candidate scan
  const float* rowp = out + ((size_t)b * NSTEP + t) * VV;
  for (int v = tid; v < VV; v += 256) {
    float x = rowp[v];
    if (x >= thr && v != (int)va) {
      int p = atomicAdd(&sflags[0], 1);
      if (p < 32) scand[p] = v;
    }
  }
  __syncthreads();
  int nc = sflags[0] < 32 ? sflags[0] : 32;

  // Phase 2: exact fp32 logits for candidates (one wave per candidate)
  const int wv_ = tid >> 6, ln = tid & 63;
  for (int ci = wv_; ci < nc; ci += 4) {
    int v = scand[ci];
    float p = 0.f;
#pragma unroll
    for (int q = 0; q < 16; ++q)
      p += h4[b * HH + ln + (q << 6)] * fcW[(size_t)v * HH + ln + (q << 6)];
#pragma unroll
    for (int d = 1; d < 64; d <<= 1) p += __shfl_xor(p, d);
    if (ln == 0)
      rkey[ci] = ((u64)ordkey(p + fcb[v]) << 32) | (u64)(0xFFFFFFFFu - (unsigned)v);
  }
  __syncthreads();
  if (tid == 0) {
    u64 bk = 0;
    for (int ci = 0; ci < nc; ++ci)
      if (rkey[ci] > bk) bk = rkey[ci];
    sflags[1] = (int)(0xFFFFFFFFu - (unsigned)(bk & 0xFFFFFFFFu));
  }
  __syncthreads();

  // Phase 3: gather next-step x fragments
  const int tok = sflags[1];
  for (int k = tid; k < EE; k += 256) {
    float xv = emb[(size_t)tok * EE + k];
    unsigned short xm = f2bf(xv);
    size_t xi = (((size_t)(b >> 4) * 16 + (k >> 5)) * 64 + ((b & 15) + (((k >> 3) & 3) << 4))) * 8 + (k & 7);
    xam[xi] = xm;
    xar[xi] = f2bf(xv - bf2f(xm));
  }
}

// ================= real step kernels =================
__global__ __launch_bounds__(256, 4) void gru_kernel(
    const unsigned short* xam, const unsigned short* xar,
    const unsigned short* him, const unsigned short* hir,
    const float* h4in, float* h4out,
    const unsigned short* wm, const unsigned short* wrs,
    const float* bih, const float* bhh,
    unsigned short* hom, unsigned short* hor) {
  __shared__ float red[4][16][65];
  gru_body(blockIdx.x, threadIdx.x, red, xam, xar, him, hir, h4in, h4out, wm, wrs, bih, bhh, hom, hor);
}

__global__ __launch_bounds__(256, 4) void fc_kernel(
    const unsigned short* ham, const unsigned short* har,
    const unsigned short* wfc, const float* fcb,
    float* out, u64* blkkeys, int t) {
  __shared__ float red[4][64][33];
  fc_body(blockIdx.x, threadIdx.x, red, ham, har, wfc, fcb, out, blkkeys, t);
}

__global__ __launch_bounds__(256) void sel_kernel(
    const float* out, const u64* blkkeys,
    const float* fcW, const float* fcb,
    const float* emb, const float* h4,
    unsigned short* xam, unsigned short* xar, int t) {
  __shared__ u64 skey[256];
  __shared__ int sflags[2];
  __shared__ int scand[32];
  __shared__ u64 rkey[32];
  sel_body(blockIdx.x, threadIdx.x, skey, sflags, scand, rkey,
           out, blkkeys, fcW, fcb, emb, h4, xam, xar, t);
}

// ================= diagnostic kernels: 32x phase body into scratch =================
__global__ __launch_bounds__(256, 4) void diag_gru(
    const unsigned short* xam, const unsigned short* xar,
    const unsigned short* him, const unsigned short* hir,
    const float* h4in, float* sc_h4,
    const unsigned short* wm, const unsigned short* wrs,
    const float* bih, const float* bhh,
    unsigned short* sc_hm, unsigned short* sc_hr) {
  __shared__ float red[4][16][65];
  for (int it = 0; it < 32; ++it) {
    gru_body(blockIdx.x, threadIdx.x, red, xam, xar, him, hir, h4in, sc_h4, wm, wrs, bih, bhh, sc_hm, sc_hr);
    __syncthreads();
  }
}

__global__ __launch_bounds__(256, 4) void diag_fc(
    const unsigned short* ham, const unsigned short* har,
    const unsigned short* wfc, const float* fcb,
    float* sc_out, u64* sc_keys) {
  __shared__ float red[4][64][33];
  for (int it = 0; it < 32; ++it) {
    fc_body(blockIdx.x, threadIdx.x, red, ham, har, wfc, fcb, sc_out, sc_keys, 0);
    __syncthreads();
  }
}

__global__ __launch_bounds__(256) void diag_sel(
    const float* out, const u64* blkkeys,
    const float* fcW, const float* fcb,
    const float* emb, const float* h4,
    unsigned short* sc_x1, unsigned short* sc_x2) {
  __shared__ u64 skey[256];
  __shared__ int sflags[2];
  __shared__ int scand[32];
  __shared__ u64 rkey[32];
  for (int it = 0; it < 32; ++it) {
    sel_body(blockIdx.x, threadIdx.x, skey, sflags, scand, rkey,
             out, blkkeys, fcW, fcb, emb, h4, sc_x1, sc_x2, NSTEP - 1);
    __syncthreads();
  }
}

// ---------- final: in-place log-softmax per (b,t) row ----------
__global__ __launch_bounds__(256) void lsm_kernel(float* __restrict__ out) {
  const int bt = blockIdx.x;
  const int tid = threadIdx.x;
  float* row = out + (size_t)bt * VV;
  float4* r4 = (float4*)row;
  __shared__ float mred[256], sred[256];
  float m = -INFINITY, s = 0.f;
  for (int i = tid; i < VV / 4; i += 256) {
    float4 v = r4[i];
#pragma unroll
    for (int c = 0; c < 4; ++c) {
      float x = (&v.x)[c];
      if (x > m) { s = s * expf(m - x) + 1.0f; m = x; }
      else s += expf(x - m);
    }
  }
  mred[tid] = m; sred[tid] = s;
  __syncthreads();
  for (int off = 128; off > 0; off >>= 1) {
    if (tid < off) {
      float m1 = mred[tid], s1 = sred[tid];
      float m2 = mred[tid + off], s2 = sred[tid + off];
      float M = fmaxf(m1, m2);
      mred[tid] = M;
      sred[tid] = s1 * expf(m1 - M) + s2 * expf(m2 - M);
    }
    __syncthreads();
  }
  const float lse = mred[0] + logf(sred[0]);
  for (int i = tid; i < VV / 4; i += 256) {
    float4 v = r4[i];
    v.x -= lse; v.y -= lse; v.z -= lse; v.w -= lse;
    r4[i] = v;
  }
}

// ---------- hT tail ----------
__global__ __launch_bounds__(256) void final_kernel(const float* __restrict__ h4,
                                                    float* __restrict__ out) {
  int i = blockIdx.x * 256 + threadIdx.x;  // 65536
  out[(size_t)NB * NSTEP * VV + i] = h4[i];
}

extern "C" void kernel_launch(void* const* d_in, const int* in_sizes, int n_in,
                              void* d_out, int out_size, void* d_ws, size_t ws_size,
                              hipStream_t stream) {
  const float* enc = (const float*)d_in[1];
  const float* emb = (const float*)d_in[2];
  const float* Wih = (const float*)d_in[3];
  const float* Whh = (const float*)d_in[4];
  const float* bih = (const float*)d_in[5];
  const float* bhh = (const float*)d_in[6];
  const float* fcW = (const float*)d_in[7];
  const float* fcb = (const float*)d_in[8];
  float* out = (float*)d_out;

  char* ws = (char*)d_ws;
  unsigned short* wfc = (unsigned short*)ws; ws += (size_t)32768000 * 2;  // 65.5 MB
  unsigned short* wcm = (unsigned short*)ws; ws += (size_t)4718592 * 2;   // 9.44 MB
  unsigned short* wcr = (unsigned short*)ws; ws += (size_t)4718592 * 2;   // 9.44 MB
  unsigned short* hAm = (unsigned short*)ws; ws += (size_t)65536 * 2;
  unsigned short* hAr = (unsigned short*)ws; ws += (size_t)65536 * 2;
  unsigned short* hBm = (unsigned short*)ws; ws += (size_t)65536 * 2;
  unsigned short* hBr = (unsigned short*)ws; ws += (size_t)65536 * 2;
  unsigned short* xam = (unsigned short*)ws; ws += (size_t)32768 * 2;
  unsigned short* xar = (unsigned short*)ws; ws += (size_t)32768 * 2;
  float* h4a = (float*)ws; ws += (size_t)NB * HH * 4;
  float* h4b = (float*)ws; ws += (size_t)NB * HH * 4;
  u64* blkkeys = (u64*)ws; ws += (size_t)NB * 1000 * 8;  // 512 KB
  // diagnostic scratch
  float* sc_out = (float*)ws; ws += (size_t)NB * NSTEP * VV * 4;  // 262 MB
  u64* sc_keys = (u64*)ws; ws += (size_t)NB * 1000 * 8;
  float* sc_h4 = (float*)ws; ws += (size_t)NB * HH * 4;
  unsigned short* sc_hm = (unsigned short*)ws; ws += (size_t)65536 * 2;
  unsigned short* sc_hr = (unsigned short*)ws; ws += (size_t)65536 * 2;
  unsigned short* sc_x1 = (unsigned short*)ws; ws += (size_t)32768 * 2;
  unsigned short* sc_x2 = (unsigned short*)ws; ws += (size_t)32768 * 2;

  prep_wfc<<<1000, 256, 0, stream>>>(fcW, wfc);
  prep_wcat<<<192, 256, 0, stream>>>(Wih, Whh, wcm, wcr);
  init_kernel<<<256, 256, 0, stream>>>(enc, emb, h4a, hAm, hAr, xam, xar);

  for (int t = 0; t < NSTEP; ++t) {
    const float* hin = (t & 1) ? h4b : h4a;
    float* hout = (t & 1) ? h4a : h4b;
    const unsigned short* him = (t & 1) ? hBm : hAm;
    const unsigned short* hir = (t & 1) ? hBr : hAr;
    unsigned short* hom = (t & 1) ? hAm : hBm;
    unsigned short* hor = (t & 1) ? hAr : hBr;
    gru_kernel<<<256, 256, 0, stream>>>(xam, xar, him, hir, hin, hout, wcm, wcr, bih, bhh, hom, hor);
    fc_kernel<<<1000, 256, 0, stream>>>(hom, hor, wfc, fcb, out, blkkeys, t);
    sel_kernel<<<64, 256, 0, stream>>>(out, blkkeys, fcW, fcb, emb, hout, xam, xar, t);
  }
  lsm_kernel<<<2048, 256, 0, stream>>>(out);
  final_kernel<<<256, 256, 0, stream>>>(h4a, out);  // t=31 wrote h4a

  // ---- diagnostics (scratch-only, after output complete): 32x each phase ----
  diag_gru<<<256, 256, 0, stream>>>(xam, xar, hAm, hAr, h4a, sc_h4, wcm, wcr, bih, bhh, sc_hm, sc_hr);
  diag_fc<<<1000, 256, 0, stream>>>(hAm, hAr, wfc, fcb, sc_out, sc_keys);
  diag_sel<<<64, 256, 0, stream>>>(out, blkkeys, fcW, fcb, emb, h4a, sc_x1, sc_x2);
}

// Round 10
// 2805.928 us; speedup vs baseline: 3.7351x; 1.9780x over previous
//
#include <hip/hip_runtime.h>

#define VV 32000
#define EE 512
#define HH 1024
#define NB 64
#define NSTEP 32

typedef __attribute__((ext_vector_type(8))) short short8;
typedef __attribute__((ext_vector_type(4))) float f32x4;
typedef unsigned long long u64;

#define MFMA16(a, b, c) __builtin_amdgcn_mfma_f32_16x16x32_bf16((a), (b), (c), 0, 0, 0)

__device__ __forceinline__ unsigned short f2bf(float f) {
  unsigned int u = __float_as_uint(f);
  u += 0x7fffu + ((u >> 16) & 1u);
  return (unsigned short)(u >> 16);
}
__device__ __forceinline__ float bf2f(unsigned short b) {
  return __uint_as_float(((unsigned int)b) << 16);
}
__device__ __forceinline__ float sigmoidf_(float x) { return 1.0f / (1.0f + expf(-x)); }
__device__ __forceinline__ unsigned int ordkey(float f) {
  unsigned int u = __float_as_uint(f);
  return u ^ ((u >> 31) ? 0xFFFFFFFFu : 0x80000000u);
}
__device__ __forceinline__ float ordkey_inv(unsigned int u) {
  return __uint_as_float((u & 0x80000000u) ? (u ^ 0x80000000u) : ~u);
}

// ---------- prep: [Wih | Whh] -> bf16 main+res fragments ----------
__global__ __launch_bounds__(256) void prep_wcat(const float* __restrict__ Wih,
                                                 const float* __restrict__ Whh,
                                                 unsigned short* __restrict__ wm,
                                                 unsigned short* __restrict__ wr) {
  int ub = blockIdx.x / 3, g = blockIdx.x % 3;
  for (int e = threadIdx.x; e < 48 * 512; e += 256) {
    int ks = e >> 9, lane = (e >> 3) & 63, j = e & 7;
    int row = g * HH + ub * 16 + (lane & 15);
    int k = ks * 32 + ((lane >> 4) << 3) + j;
    float f = (k < EE) ? Wih[(size_t)row * EE + k] : Whh[(size_t)row * HH + (k - EE)];
    unsigned short m_ = f2bf(f);
    size_t idx = (((size_t)(ub * 3 + g) * 48 + ks) * 64 + lane) * 8 + j;
    wm[idx] = m_;
    wr[idx] = f2bf(f - bf2f(m_));
  }
}

// ---------- prep: fcW -> bf16 single fragments ----------
__global__ __launch_bounds__(256) void prep_wfc(const float* __restrict__ fcW,
                                                unsigned short* __restrict__ wfc) {
  int vg = blockIdx.x;
  for (int e = threadIdx.x; e < 32768; e += 256) {
    int ks = e >> 10, n = (e >> 9) & 1, lane = (e >> 3) & 63, j = e & 7;
    int v = vg * 32 + n * 16 + (lane & 15);
    int k = ks * 32 + ((lane >> 4) << 3) + j;
    wfc[(((size_t)vg * 32 + ks) * 2 + n) * 512 + lane * 8 + j] = f2bf(fcW[(size_t)v * HH + k]);
  }
}

// ---------- init: h0 (row-major + frags), x0 = emb[SOS], zero cnt ----------
__global__ __launch_bounds__(256) void init_kernel(
    const float* __restrict__ enc, const float* __restrict__ emb, float* __restrict__ h4a,
    unsigned short* __restrict__ ham, unsigned short* __restrict__ har,
    unsigned short* __restrict__ xam, unsigned short* __restrict__ xar,
    int* __restrict__ cnt) {
  int i = blockIdx.x * 256 + threadIdx.x;  // 65536
  int b = i >> 10, u = i & 1023;
  float hv = enc[i];
  h4a[i] = hv;
  unsigned short m_ = f2bf(hv);
  size_t idx = (((size_t)(b >> 4) * 32 + (u >> 5)) * 64 + ((b & 15) + (((u >> 3) & 3) << 4))) * 8 + (u & 7);
  ham[idx] = m_;
  har[idx] = f2bf(hv - bf2f(m_));
  if (i < NB * EE) {
    int b2 = i >> 9, k = i & 511;
    float xv = emb[EE + k];  // token SOS=1
    unsigned short xm = f2bf(xv);
    size_t xi = (((size_t)(b2 >> 4) * 16 + (k >> 5)) * 64 + ((b2 & 15) + (((k >> 3) & 3) << 4))) * 8 + (k & 7);
    xam[xi] = xm;
    xar[xi] = f2bf(xv - bf2f(xm));
  }
  if (i < NB) cnt[i] = 0;
}

// ================= phase bodies (exact r5 logic) =================

__device__ __forceinline__ void gru_body(
    int bid, int tid, float (*red)[16][65],
    const unsigned short* xam, const unsigned short* xar,
    const unsigned short* him, const unsigned short* hir,
    const float* h4in, float* h4out,
    const unsigned short* wm, const unsigned short* wrs,
    const float* bih, const float* bhh,
    unsigned short* hom, unsigned short* hor) {
  const int lane = tid & 63, w = tid >> 6;
  const int ub = bid >> 2, mg = bid & 3;
  f32x4 aR{}, aZ{}, aNX{}, aNH{};
  const short8* XM = (const short8*)xam;
  const short8* XR = (const short8*)xar;
  const short8* HM = (const short8*)him;
  const short8* HR = (const short8*)hir;
  const short8* WM = (const short8*)wm;
  const short8* WR = (const short8*)wrs;
#pragma unroll
  for (int s = 0; s < 12; ++s) {
    int ks = w * 12 + s;
    short8 am, ar;
    if (ks < 16) {
      int o = (mg * 16 + ks) * 64 + lane;
      am = XM[o]; ar = XR[o];
    } else {
      int o = (mg * 32 + (ks - 16)) * 64 + lane;
      am = HM[o]; ar = HR[o];
    }
    {
      int o = ((ub * 3 + 0) * 48 + ks) * 64 + lane;
      short8 wmv = WM[o], wrv = WR[o];
      aR = MFMA16(am, wmv, aR); aR = MFMA16(ar, wmv, aR); aR = MFMA16(am, wrv, aR);
    }
    {
      int o = ((ub * 3 + 1) * 48 + ks) * 64 + lane;
      short8 wmv = WM[o], wrv = WR[o];
      aZ = MFMA16(am, wmv, aZ); aZ = MFMA16(ar, wmv, aZ); aZ = MFMA16(am, wrv, aZ);
    }
    {
      int o = ((ub * 3 + 2) * 48 + ks) * 64 + lane;
      short8 wmv = WM[o], wrv = WR[o];
      if (ks < 16) {
        aNX = MFMA16(am, wmv, aNX); aNX = MFMA16(ar, wmv, aNX); aNX = MFMA16(am, wrv, aNX);
      } else {
        aNH = MFMA16(am, wmv, aNH); aNH = MFMA16(ar, wmv, aNH); aNH = MFMA16(am, wrv, aNH);
      }
    }
  }
#pragma unroll
  for (int reg = 0; reg < 4; ++reg) {
    int rr = ((lane >> 4) << 2) + reg, c = lane & 15;
    red[w][rr][c] = aR[reg];
    red[w][rr][16 + c] = aZ[reg];
    red[w][rr][32 + c] = aNX[reg];
    red[w][rr][48 + c] = aNH[reg];
  }
  __syncthreads();
  const int mrow = tid >> 4, uu = tid & 15;
  float R = 0.f, Z = 0.f, NX = 0.f, NH = 0.f;
#pragma unroll
  for (int q = 0; q < 4; ++q) {
    R += red[q][mrow][uu];
    Z += red[q][mrow][16 + uu];
    NX += red[q][mrow][32 + uu];
    NH += red[q][mrow][48 + uu];
  }
  const int b = mg * 16 + mrow, u = ub * 16 + uu;
  float r = sigmoidf_(R + bih[u] + bhh[u]);
  float z = sigmoidf_(Z + bih[HH + u] + bhh[HH + u]);
  float n = tanhf(NX + bih[2 * HH + u] + r * (NH + bhh[2 * HH + u]));
  float hold = h4in[b * HH + u];
  float hn = (1.0f - z) * n + z * hold;
  h4out[b * HH + u] = hn;
  unsigned short m_ = f2bf(hn);
  size_t idx = (((size_t)(b >> 4) * 32 + (u >> 5)) * 64 + ((b & 15) + (((u >> 3) & 3) << 4))) * 8 + (u & 7);
  hom[idx] = m_;
  hor[idx] = f2bf(hn - bf2f(m_));
}

__device__ __forceinline__ void fc_body(
    int bid, int tid, float (*red)[64][33],
    const unsigned short* ham, const unsigned short* har,
    const unsigned short* wfc, const float* fcb,
    float* out, u64* blkkeys, int t) {
  const int lane = tid & 63, w = tid >> 6;
  const int vg = bid;
  f32x4 acc[4][2] = {};
  const short8* HM = (const short8*)ham;
  const short8* HR = (const short8*)har;
  const short8* W = (const short8*)wfc;
#pragma unroll
  for (int s = 0; s < 8; ++s) {
    int ks = w * 8 + s;
    short8 am[4], ar[4], wv[2];
#pragma unroll
    for (int m = 0; m < 4; ++m) {
      int o = (m * 32 + ks) * 64 + lane;
      am[m] = HM[o]; ar[m] = HR[o];
    }
#pragma unroll
    for (int nt = 0; nt < 2; ++nt) wv[nt] = W[((vg * 32 + ks) * 2 + nt) * 64 + lane];
#pragma unroll
    for (int m = 0; m < 4; ++m)
#pragma unroll
      for (int nt = 0; nt < 2; ++nt) {
        acc[m][nt] = MFMA16(am[m], wv[nt], acc[m][nt]);
        acc[m][nt] = MFMA16(ar[m], wv[nt], acc[m][nt]);
      }
  }
#pragma unroll
  for (int m = 0; m < 4; ++m)
#pragma unroll
    for (int nt = 0; nt < 2; ++nt)
#pragma unroll
      for (int reg = 0; reg < 4; ++reg)
        red[w][m * 16 + ((lane >> 4) << 2) + reg][nt * 16 + (lane & 15)] = acc[m][nt][reg];
  __syncthreads();
  const int b = tid >> 2, c0 = (tid & 3) << 3;
  u64 k1 = 0;
  size_t ro = ((size_t)b * NSTEP + t) * VV + (size_t)vg * 32 + c0;
#pragma unroll
  for (int e = 0; e < 8; ++e) {
    int c = c0 + e;
    float v = red[0][b][c] + red[1][b][c] + red[2][b][c] + red[3][b][c] + fcb[vg * 32 + c];
    out[ro + e] = v;
    u64 key = ((u64)ordkey(v) << 32) | (u64)(0xFFFFFFFFu - (unsigned)(vg * 32 + c));
    if (key > k1) k1 = key;
  }
  {
    u64 o1 = __shfl_xor(k1, 1, 64);
    if (o1 > k1) k1 = o1;
    u64 o2 = __shfl_xor(k1, 2, 64);
    if (o2 > k1) k1 = o2;
  }
  if ((tid & 3) == 0) blkkeys[(size_t)b * 1000 + vg] = k1;
}

// ================= real step kernels =================
__global__ __launch_bounds__(256, 4) void gru_kernel(
    const unsigned short* xam, const unsigned short* xar,
    const unsigned short* him, const unsigned short* hir,
    const float* h4in, float* h4out,
    const unsigned short* wm, const unsigned short* wrs,
    const float* bih, const float* bhh,
    unsigned short* hom, unsigned short* hor) {
  __shared__ float red[4][16][65];
  gru_body(blockIdx.x, threadIdx.x, red, xam, xar, him, hir, h4in, h4out, wm, wrs, bih, bhh, hom, hor);
}

// (256,2): lift VGPR cap 64 -> ~256 so the W-stream can pipeline deeply (MLP fix)
__global__ __launch_bounds__(256, 2) void fc_kernel(
    const unsigned short* ham, const unsigned short* har,
    const unsigned short* wfc, const float* fcb,
    float* out, u64* blkkeys, int t) {
  __shared__ float red[4][64][33];
  fc_body(blockIdx.x, threadIdx.x, red, ham, har, wfc, fcb, out, blkkeys, t);
}

// ---------- sel1: parallel quarter-row candidate scan (4 blocks per b) ----------
__global__ __launch_bounds__(256) void sel1_kernel(
    const float* __restrict__ out, const u64* __restrict__ blkkeys,
    int* __restrict__ cnt, int* __restrict__ cand, int t) {
  const int b = blockIdx.x >> 2, q = blockIdx.x & 3;
  const int tid = threadIdx.x;
  __shared__ u64 skey[256];
  const u64* kb = blkkeys + (size_t)b * 1000;
  u64 mk = 0;
  for (int i = tid; i < 1000; i += 256) {
    u64 k = kb[i];
    if (k > mk) mk = k;
  }
  skey[tid] = mk;
  __syncthreads();
  for (int off = 128; off > 0; off >>= 1) {
    if (tid < off && skey[tid + off] > skey[tid]) skey[tid] = skey[tid + off];
    __syncthreads();
  }
  const float Mf = ordkey_inv((unsigned)(skey[0] >> 32));
  const float thr = Mf - 0.10f;  // r5 margin, unchanged
  const float* rowp = out + ((size_t)b * NSTEP + t) * VV;
  for (int v = q * (VV / 4) + tid; v < (q + 1) * (VV / 4); v += 256) {
    if (rowp[v] >= thr) {
      int p = atomicAdd(&cnt[b], 1);
      if (p < 256) cand[b * 256 + p] = v;
    }
  }
}

// ---------- sel2: exact fp32 refine + argmax + emb gather + cnt reset ----------
__global__ __launch_bounds__(256) void sel2_kernel(
    int* __restrict__ cnt, const int* __restrict__ cand,
    const float* __restrict__ fcW, const float* __restrict__ fcb,
    const float* __restrict__ emb, const float* __restrict__ h4,
    unsigned short* __restrict__ xam, unsigned short* __restrict__ xar) {
  const int b = blockIdx.x, tid = threadIdx.x;
  __shared__ int scand[256];
  __shared__ u64 rkey[256];
  __shared__ int stok;
  int n = cnt[b];
  if (n > 256) n = 256;
  for (int i = tid; i < n; i += 256) scand[i] = cand[b * 256 + i];
  __syncthreads();
  const int w = tid >> 6, ln = tid & 63;
  for (int ci = w; ci < n; ci += 4) {
    int v = scand[ci];
    float p = 0.f;
#pragma unroll
    for (int q = 0; q < 16; ++q)
      p += h4[b * HH + ln + (q << 6)] * fcW[(size_t)v * HH + ln + (q << 6)];
#pragma unroll
    for (int d = 1; d < 64; d <<= 1) p += __shfl_xor(p, d);
    if (ln == 0)
      rkey[ci] = ((u64)ordkey(p + fcb[v]) << 32) | (u64)(0xFFFFFFFFu - (unsigned)v);
  }
  __syncthreads();
  if (tid == 0) {
    u64 bk = 0;
    for (int ci = 0; ci < n; ++ci)
      if (rkey[ci] > bk) bk = rkey[ci];
    stok = (int)(0xFFFFFFFFu - (unsigned)(bk & 0xFFFFFFFFu));
    cnt[b] = 0;  // reset for next step
  }
  __syncthreads();
  const int tok = stok;
  for (int k = tid; k < EE; k += 256) {
    float xv = emb[(size_t)tok * EE + k];
    unsigned short xm = f2bf(xv);
    size_t xi = (((size_t)(b >> 4) * 16 + (k >> 5)) * 64 + ((b & 15) + (((k >> 3) & 3) << 4))) * 8 + (k & 7);
    xam[xi] = xm;
    xar[xi] = f2bf(xv - bf2f(xm));
  }
}

// ================= diagnostic: fc body 16x into scratch =================
__global__ __launch_bounds__(256, 2) void diag_fc(
    const unsigned short* ham, const unsigned short* har,
    const unsigned short* wfc, const float* fcb,
    float* sc_out, u64* sc_keys) {
  __shared__ float red[4][64][33];
  for (int it = 0; it < 16; ++it) {
    fc_body(blockIdx.x, threadIdx.x, red, ham, har, wfc, fcb, sc_out, sc_keys, 0);
    __syncthreads();
  }
}

// ---------- final: in-place log-softmax per (b,t) row ----------
__global__ __launch_bounds__(256) void lsm_kernel(float* __restrict__ out) {
  const int bt = blockIdx.x;
  const int tid = threadIdx.x;
  float* row = out + (size_t)bt * VV;
  float4* r4 = (float4*)row;
  __shared__ float mred[256], sred[256];
  float m = -INFINITY, s = 0.f;
  for (int i = tid; i < VV / 4; i += 256) {
    float4 v = r4[i];
#pragma unroll
    for (int c = 0; c < 4; ++c) {
      float x = (&v.x)[c];
      if (x > m) { s = s * expf(m - x) + 1.0f; m = x; }
      else s += expf(x - m);
    }
  }
  mred[tid] = m; sred[tid] = s;
  __syncthreads();
  for (int off = 128; off > 0; off >>= 1) {
    if (tid < off) {
      float m1 = mred[tid], s1 = sred[tid];
      float m2 = mred[tid + off], s2 = sred[tid + off];
      float M = fmaxf(m1, m2);
      mred[tid] = M;
      sred[tid] = s1 * expf(m1 - M) + s2 * expf(m2 - M);
    }
    __syncthreads();
  }
  const float lse = mred[0] + logf(sred[0]);
  for (int i = tid; i < VV / 4; i += 256) {
    float4 v = r4[i];
    v.x -= lse; v.y -= lse; v.z -= lse; v.w -= lse;
    r4[i] = v;
  }
}

// ---------- hT tail ----------
__global__ __launch_bounds__(256) void final_kernel(const float* __restrict__ h4,
                                                    float* __restrict__ out) {
  int i = blockIdx.x * 256 + threadIdx.x;  // 65536
  out[(size_t)NB * NSTEP * VV + i] = h4[i];
}

extern "C" void kernel_launch(void* const* d_in, const int* in_sizes, int n_in,
                              void* d_out, int out_size, void* d_ws, size_t ws_size,
                              hipStream_t stream) {
  const float* enc = (const float*)d_in[1];
  const float* emb = (const float*)d_in[2];
  const float* Wih = (const float*)d_in[3];
  const float* Whh = (const float*)d_in[4];
  const float* bih = (const float*)d_in[5];
  const float* bhh = (const float*)d_in[6];
  const float* fcW = (const float*)d_in[7];
  const float* fcb = (const float*)d_in[8];
  float* out = (float*)d_out;

  char* ws = (char*)d_ws;
  unsigned short* wfc = (unsigned short*)ws; ws += (size_t)32768000 * 2;  // 65.5 MB
  unsigned short* wcm = (unsigned short*)ws; ws += (size_t)4718592 * 2;   // 9.44 MB
  unsigned short* wcr = (unsigned short*)ws; ws += (size_t)4718592 * 2;   // 9.44 MB
  unsigned short* hAm = (unsigned short*)ws; ws += (size_t)65536 * 2;
  unsigned short* hAr = (unsigned short*)ws; ws += (size_t)65536 * 2;
  unsigned short* hBm = (unsigned short*)ws; ws += (size_t)65536 * 2;
  unsigned short* hBr = (unsigned short*)ws; ws += (size_t)65536 * 2;
  unsigned short* xam = (unsigned short*)ws; ws += (size_t)32768 * 2;
  unsigned short* xar = (unsigned short*)ws; ws += (size_t)32768 * 2;
  float* h4a = (float*)ws; ws += (size_t)NB * HH * 4;
  float* h4b = (float*)ws; ws += (size_t)NB * HH * 4;
  u64* blkkeys = (u64*)ws; ws += (size_t)NB * 1000 * 8;  // 512 KB
  int* cnt = (int*)ws; ws += (size_t)NB * 4;
  int* cand = (int*)ws; ws += (size_t)NB * 256 * 4;  // 64 KB
  // diagnostic scratch
  float* sc_out = (float*)ws; ws += (size_t)NB * NSTEP * VV * 4;  // 262 MB
  u64* sc_keys = (u64*)ws; ws += (size_t)NB * 1000 * 8;

  prep_wfc<<<1000, 256, 0, stream>>>(fcW, wfc);
  prep_wcat<<<192, 256, 0, stream>>>(Wih, Whh, wcm, wcr);
  init_kernel<<<256, 256, 0, stream>>>(enc, emb, h4a, hAm, hAr, xam, xar, cnt);

  for (int t = 0; t < NSTEP; ++t) {
    const float* hin = (t & 1) ? h4b : h4a;
    float* hout = (t & 1) ? h4a : h4b;
    const unsigned short* him = (t & 1) ? hBm : hAm;
    const unsigned short* hir = (t & 1) ? hBr : hAr;
    unsigned short* hom = (t & 1) ? hAm : hBm;
    unsigned short* hor = (t & 1) ? hAr : hBr;
    gru_kernel<<<256, 256, 0, stream>>>(xam, xar, him, hir, hin, hout, wcm, wcr, bih, bhh, hom, hor);
    fc_kernel<<<1000, 256, 0, stream>>>(hom, hor, wfc, fcb, out, blkkeys, t);
    sel1_kernel<<<256, 256, 0, stream>>>(out, blkkeys, cnt, cand, t);
    sel2_kernel<<<64, 256, 0, stream>>>(cnt, cand, fcW, fcb, emb, hout, xam, xar);
  }
  lsm_kernel<<<2048, 256, 0, stream>>>(out);
  final_kernel<<<256, 256, 0, stream>>>(h4a, out);  // t=31 wrote h4a

  // ---- diagnostic (scratch-only, after output complete): 16x fc body ----
  diag_fc<<<1000, 256, 0, stream>>>(hAm, hAr, wfc, fcb, sc_out, sc_keys);
}